// Round 4
// baseline (461.749 us; speedup 1.0000x reference)
//
#include <hip/hip_runtime.h>
#include <hip/hip_bf16.h>

#define N_NODES 100000
#define N_EDGES 1600000
#define N_EL    200000
// Round 19:
//  (1) rank atomics (proven throughput wall ~60us: 1.6M global RMW x ~12cy / 128
//      channels, MLP-invariant) replaced by atomic-free 2-level counting sort:
//      fat1{gemm1 + LDS chunk-histogram} -> scanB (782x782 matrix scan,
//      last-block) -> csrC (bucket-scatter, LDS cursors) -> csrD (per-bucket
//      degree/rowptr/dinv/col + t-prescale fused). Zero global atomics.
//  (2) gathers: 8B/lane (uint2) -> 2 rows per load instr (4 for D=64); halves
//      VMEM instruction count; cross-half combine via shfl_xor.
//  (3) prescale pass + lrp/boff split removed (csrD fuses prescale; direct rowptr).

#define NBKT 782                    // node buckets of 128
#define NCHK 782                    // edge chunks of 2048
#define CHKE 2048
#define DCAP 2688                   // bucket edge capacity (mean 2048, sd ~45)
#define GT_GEMM ((N_NODES + 63) / 64)   // 1563
#define GRID_FAT (3 * NCHK)             // 2346: 2 gemm : 1 hist

typedef unsigned int uint32;
typedef unsigned short ushort16;
typedef __attribute__((ext_vector_type(8))) short short8;   // 8 bf16
typedef __attribute__((ext_vector_type(4))) float f32x4;

static __device__ __forceinline__ ushort16 f2bf(float f) {
    uint32 u = __float_as_uint(f);
    u += 0x7fffu + ((u >> 16) & 1u);      // RNE
    return (ushort16)(u >> 16);
}
static __device__ __forceinline__ float bf_lo(uint32 p) { return __uint_as_float(p << 16); }
static __device__ __forceinline__ float bf_hi(uint32 p) { return __uint_as_float(p & 0xffff0000u); }
static __device__ __forceinline__ uint32 pack2(float lo, float hi) {
    return (uint32)f2bf(lo) | ((uint32)f2bf(hi) << 16);
}

// ---------------- 782-wide exclusive scan helper (256 thr, 4 seq/thread) --------
template <bool AT>
static __device__ __forceinline__ int scan782(const int* __restrict__ in,
                                              int* __restrict__ outv,
                                              int* s, int tid) {
    __syncthreads();
    int v[4]; int sum = 0;
    int i0 = tid * 4;
#pragma unroll
    for (int i = 0; i < 4; ++i) {
        int idx = i0 + i;
        int x = 0;
        if (idx < NBKT)
            x = AT ? __hip_atomic_load(&in[idx], __ATOMIC_ACQUIRE,
                                       __HIP_MEMORY_SCOPE_AGENT)
                   : in[idx];
        v[i] = x; sum += x;
    }
    s[tid] = sum;
    __syncthreads();
    for (int off = 1; off < 256; off <<= 1) {
        int u = (tid >= off) ? s[tid - off] : 0;
        __syncthreads();
        s[tid] += u;
        __syncthreads();
    }
    int excl = s[tid] - sum;
    int total = s[255];
    int run = excl;
#pragma unroll
    for (int i = 0; i < 4; ++i) {
        int idx = i0 + i;
        if (idx < NBKT) outv[idx] = run;
        run += v[i];
    }
    return total;
}

// ---------------- scanB: per-bucket chunk-scan of H; last block scans totals ----
__global__ __launch_bounds__(256) void k_scanB(const int* __restrict__ H,
        int* __restrict__ CO, int* __restrict__ TT, int* __restrict__ BB,
        int* __restrict__ cnt) {
    __shared__ int s[256];
    __shared__ int lastflag;
    int b = blockIdx.x, tid = threadIdx.x;
    int total = scan782<false>(H + (size_t)b * NBKT, CO + (size_t)b * NBKT, s, tid);
    if (tid == 0) {
        __hip_atomic_store(&TT[b], total, __ATOMIC_RELEASE, __HIP_MEMORY_SCOPE_AGENT);
        int c = __hip_atomic_fetch_add(cnt, 1, __ATOMIC_ACQ_REL,
                                       __HIP_MEMORY_SCOPE_AGENT);
        lastflag = (c == NBKT - 1);
    }
    __syncthreads();
    if (!lastflag) return;
    int gt = scan782<true>(TT, BB, s, tid);
    __syncthreads();
    if (tid == 0) BB[NBKT] = gt;
}

// ---------------- csrC: bucket-scatter edges (LDS cursors, no global atomics) ---
__global__ __launch_bounds__(256) void k_csrC(const int* __restrict__ src,
        const int* __restrict__ dst, const int* __restrict__ CO,
        const int* __restrict__ BB, long long* __restrict__ ed) {
    __shared__ int cur[NBKT];
    int c = blockIdx.x, tid = threadIdx.x;
    for (int i = tid; i < NBKT; i += 256)
        cur[i] = BB[i] + CO[(size_t)i * NBKT + c];
    __syncthreads();
    int e0 = c * CHKE;
#pragma unroll
    for (int kk = 0; kk < 8; ++kk) {
        int e = e0 + kk * 256 + tid;
        if (e < N_EDGES) {
            int sE = src[e], dE = dst[e];
            int pos = atomicAdd(&cur[dE >> 7], 1);
            long long pv = (unsigned int)sE | ((long long)(unsigned int)dE << 32);
            __builtin_nontemporal_store(pv, &ed[pos]);
        }
    }
}

// ---------------- csrD: per-bucket degree/scan/rowptr/dinv/col + t prescale -----
__global__ __launch_bounds__(256) void k_csrD(const long long* __restrict__ ed,
        const int* __restrict__ BB, int* __restrict__ rowptr,
        float* __restrict__ dinv, int* __restrict__ col, uint32* __restrict__ t32) {
    __shared__ long long eds[DCAP];
    __shared__ int deg[128], scn[128], cur[128];
    __shared__ float dv[128];
    int b = blockIdx.x, tid = threadIdx.x;
    int base = BB[b], lim = BB[b + 1];
    int n = lim - base;
    bool cached = (n <= DCAP);
    if (tid < 128) deg[tid] = 0;
    __syncthreads();
    for (int i = tid; i < n; i += 256) {
        long long e = ed[base + i];
        if (cached) eds[i] = e;
        int d = (int)(e >> 32);
        atomicAdd(&deg[d & 127], 1);
    }
    __syncthreads();
    if (tid < 128) scn[tid] = deg[tid];
    __syncthreads();
    for (int off = 1; off < 128; off <<= 1) {
        int u = 0;
        if (tid < 128 && tid >= off) u = scn[tid - off];
        __syncthreads();
        if (tid < 128) scn[tid] += u;
        __syncthreads();
    }
    if (tid < 128) {
        int excl = scn[tid] - deg[tid];
        cur[tid] = excl;
        int node = b * 128 + tid;
        if (node < N_NODES) {
            rowptr[node] = base + excl;
            float di = rsqrtf((float)(deg[tid] + 1));
            dinv[node] = di;
            dv[tid] = di;
        }
    }
    if (b == NBKT - 1 && tid == 0) rowptr[N_NODES] = BB[NBKT];
    __syncthreads();
    for (int i = tid; i < n; i += 256) {
        long long e = cached ? eds[i] : ed[base + i];
        int sE = (int)(e & 0xffffffff);
        int d = (int)(e >> 32);
        int p = atomicAdd(&cur[d & 127], 1);
        col[base + p] = sE;
    }
    __syncthreads();
    // prescale layer-1 t rows of this bucket by dinv[node]
    for (int idx = tid; idx < 128 * 64; idx += 256) {
        int ni = idx >> 6;
        int node = b * 128 + ni;
        if (node < N_NODES) {
            int k = idx & 63;
            size_t a = (size_t)node * 64 + k;
            uint32 p = t32[a];
            float di = dv[ni];
            t32[a] = pack2(bf_lo(p) * di, bf_hi(p) * di);
        }
    }
}

// ---------------- A-fragment loaders ----------------
static __device__ __forceinline__ short8 load_afrag(const float* arow, int off) {
    float4 a0 = *(const float4*)(arow + off);
    float4 a1 = *(const float4*)(arow + off + 4);
    short8 af;
    af[0] = (short)f2bf(a0.x); af[1] = (short)f2bf(a0.y);
    af[2] = (short)f2bf(a0.z); af[3] = (short)f2bf(a0.w);
    af[4] = (short)f2bf(a1.x); af[5] = (short)f2bf(a1.y);
    af[6] = (short)f2bf(a1.z); af[7] = (short)f2bf(a1.w);
    return af;
}
static __device__ __forceinline__ short8 load_afrag(const ushort16* arow, int off) {
    return *(const short8*)(arow + off);   // 16B aligned
}

// ---- MFMA GEMM body: t[n,0:D] = bf16( [dinv[n]] * (A[n,:128] @ W[128,D]) ) ----
template <int D, typename AT, bool SCALE, int OS>
static __device__ __forceinline__ void gemm_body(int bid, const AT* __restrict__ A,
        const float* __restrict__ W, const float* __restrict__ dinv,
        ushort16* __restrict__ C, short* sB) {
    constexpr int NT = D / 16;                 // 8 (D=128) or 4 (D=64)
    constexpr int LNT = (NT == 8) ? 3 : 2;
    int tid = threadIdx.x;

    // stage W -> LDS in B-fragment order; 8 consecutive shorts per thread ->
    // ds_write_b128, conflict-free.
    constexpr int COMBOS = 4 * 4 * NT * 16;    // 2048 / 1024
    for (int cc = tid; cc < COMBOS; cc += 256) {
        int nn = cc & 15;
        int nt = (cc >> 4) & (NT - 1);
        int q  = (cc >> (4 + LNT)) & 3;
        int kt = cc >> (6 + LNT);
        short8 pk;
#pragma unroll
        for (int j = 0; j < 8; ++j)
            pk[j] = (short)f2bf(W[(kt * 32 + q * 8 + j) * D + nt * 16 + nn]);
        *(short8*)&sB[(((kt * NT + nt) * 64) + q * 16 + nn) * 8] = pk;
    }
    __syncthreads();

    int w = tid >> 6;
    int l = tid & 63;
    int q = l >> 4;
    int nn15 = l & 15;
    int m0 = bid * 64 + w * 16;

    f32x4 acc[NT];
#pragma unroll
    for (int i = 0; i < NT; ++i) acc[i] = (f32x4){0.f, 0.f, 0.f, 0.f};

    int m = m0 + nn15;
    m = min(m, N_NODES - 1);                    // tail clamp (loads only)
    const AT* arow = A + (size_t)m * 128;

#pragma unroll
    for (int kt = 0; kt < 4; ++kt) {
        short8 af = load_afrag(arow, kt * 32 + q * 8);
#pragma unroll
        for (int nt = 0; nt < NT; ++nt) {
            short8 bf = *(const short8*)&sB[((kt * NT + nt) * 64 + l) * 8];
            acc[nt] = __builtin_amdgcn_mfma_f32_16x16x32_bf16(af, bf, acc[nt], 0, 0, 0);
        }
    }

    float4 dvv;
    if constexpr (SCALE) dvv = *(const float4*)(dinv + m0 + 4 * q);
    const float* dvp = (const float*)&dvv;
#pragma unroll
    for (int nt = 0; nt < NT; ++nt) {
#pragma unroll
        for (int r = 0; r < 4; ++r) {
            int node = m0 + q * 4 + r;
            if (node < N_NODES) {
                float val = acc[nt][r];
                if constexpr (SCALE) val *= dvp[r];
                C[(size_t)node * OS + nt * 16 + nn15] = f2bf(val);
            }
        }
    }
}

template <int D, typename AT, bool SCALE, int OS>
__global__ __launch_bounds__(256, 5) void k_gemm_mfma(const AT* __restrict__ A,
        const float* __restrict__ W, const float* __restrict__ dinv,
        ushort16* __restrict__ C) {
    __shared__ short sB[4 * (D / 16) * 64 * 8];
    gemm_body<D, AT, SCALE, OS>(blockIdx.x, A, W, dinv, C, sB);
}

// ------- fat1: GEMM1 + chunk LDS histogram, 2:1 interleaved ---------------------
__global__ __launch_bounds__(256, 5) void k_fat1(const float* __restrict__ A,
        const float* __restrict__ W, ushort16* __restrict__ C,
        const int* __restrict__ dst, int* __restrict__ H) {
    __shared__ __align__(16) char smem[32768];
    unsigned bid = blockIdx.x;
    unsigned g = bid / 3u;
    unsigned rem = bid - g * 3u;
    int tid = threadIdx.x;
    if (rem < 2u) {                             // gemm role
        unsigned gid = g * 2u + rem;
        if (gid < GT_GEMM)
            gemm_body<128, float, false, 128>(gid, A, W, nullptr, C, (short*)smem);
    } else {                                    // hist role: chunk g
        int* hist = (int*)smem;
        for (int i = tid; i < NBKT; i += 256) hist[i] = 0;
        __syncthreads();
        int e0 = (int)g * CHKE;
#pragma unroll
        for (int kk = 0; kk < 8; ++kk) {
            int e = e0 + kk * 256 + tid;
            if (e < N_EDGES) atomicAdd(&hist[dst[e] >> 7], 1);
        }
        __syncthreads();
        for (int i = tid; i < NBKT; i += 256)
            H[(size_t)i * NBKT + g] = hist[i];
    }
}

// ---------------- gather, D=128: 8B/lane, 2 rows per load instruction -----------
// t prescaled by dinv[src]; pads -> zero row t[N_NODES].
template <bool RELU>
__global__ void k_gather128(const int* __restrict__ rowptr, const int* __restrict__ col,
                            const float* __restrict__ dinv, const uint32* __restrict__ t,
                            const float* __restrict__ b, uint32* __restrict__ outbuf) {
    __shared__ int sc[4][64];
    int tid = threadIdx.x;
    unsigned wid = (blockIdx.x * 256u + tid) >> 6;
    if (wid >= N_NODES) return;
    int w = tid >> 6;
    int lane = tid & 63;
    int h = lane >> 5;              // which row of each pair this half-wave reads
    int k = lane & 31;              // uint2 index within row (dims 4k..4k+3)
    int beg = rowptr[wid], end = rowptr[wid + 1];
    float a0 = 0.f, a1 = 0.f, a2 = 0.f, a3 = 0.f;
    if (h == 0) {                    // self-loop term counted once
        uint2 p = ((const uint2*)(t + (size_t)wid * 64))[k];
        a0 = bf_lo(p.x); a1 = bf_hi(p.x); a2 = bf_lo(p.y); a3 = bf_hi(p.y);
    }
    for (int base = beg; base < end; base += 64) {
        int cnt = min(end - base, 64);
        int c = N_NODES;
        if (lane < cnt) c = col[base + lane];
        sc[w][lane] = c;             // same-wave LDS, no barrier needed
        int nb = (cnt + 7) >> 3;
        for (int j8 = 0; j8 < nb; ++j8) {
            int j = j8 << 3;
            int r0 = sc[w][j + 0 + h];
            int r1 = sc[w][j + 2 + h];
            int r2 = sc[w][j + 4 + h];
            int r3 = sc[w][j + 6 + h];
            uint2 v0 = ((const uint2*)(t + (size_t)r0 * 64))[k];
            uint2 v1 = ((const uint2*)(t + (size_t)r1 * 64))[k];
            uint2 v2 = ((const uint2*)(t + (size_t)r2 * 64))[k];
            uint2 v3 = ((const uint2*)(t + (size_t)r3 * 64))[k];
            a0 += (bf_lo(v0.x) + bf_lo(v1.x)) + (bf_lo(v2.x) + bf_lo(v3.x));
            a1 += (bf_hi(v0.x) + bf_hi(v1.x)) + (bf_hi(v2.x) + bf_hi(v3.x));
            a2 += (bf_lo(v0.y) + bf_lo(v1.y)) + (bf_lo(v2.y) + bf_lo(v3.y));
            a3 += (bf_hi(v0.y) + bf_hi(v1.y)) + (bf_hi(v2.y) + bf_hi(v3.y));
        }
    }
    a0 += __shfl_xor(a0, 32);
    a1 += __shfl_xor(a1, 32);
    a2 += __shfl_xor(a2, 32);
    a3 += __shfl_xor(a3, 32);
    if (h == 0) {
        float di = dinv[wid];
        float4 bb = ((const float4*)b)[k];
        float o0 = fmaf(di, a0, bb.x);
        float o1 = fmaf(di, a1, bb.y);
        float o2 = fmaf(di, a2, bb.z);
        float o3 = fmaf(di, a3, bb.w);
        if (RELU) {
            o0 = fmaxf(o0, 0.f); o1 = fmaxf(o1, 0.f);
            o2 = fmaxf(o2, 0.f); o3 = fmaxf(o3, 0.f);
        }
        unsigned long long pv = (unsigned long long)pack2(o0, o1)
                              | ((unsigned long long)pack2(o2, o3) << 32);
        __builtin_nontemporal_store(pv,
            (unsigned long long*)(outbuf + (size_t)wid * 64) + k);
    }
}

// ---- gather, D=64 (t rows stride 64 uint32, payload 32): 4 rows per instr ------
__global__ void k_gather64(const int* __restrict__ rowptr, const int* __restrict__ col,
                           const float* __restrict__ dinv, const uint32* __restrict__ t,
                           const float* __restrict__ b, uint32* __restrict__ outbuf) {
    __shared__ int sc[4][64];
    int tid = threadIdx.x;
    unsigned wid = (blockIdx.x * 256u + tid) >> 6;
    if (wid >= N_NODES) return;
    int w = tid >> 6;
    int lane = tid & 63;
    int h = lane >> 4;              // 0..3: which row of each quad
    int k = lane & 15;              // uint2 index (dims 4k..4k+3 of 64)
    int beg = rowptr[wid], end = rowptr[wid + 1];
    float a0 = 0.f, a1 = 0.f, a2 = 0.f, a3 = 0.f;
    if (h == 0) {
        uint2 p = ((const uint2*)(t + (size_t)wid * 64))[k];
        a0 = bf_lo(p.x); a1 = bf_hi(p.x); a2 = bf_lo(p.y); a3 = bf_hi(p.y);
    }
    for (int base = beg; base < end; base += 64) {
        int cnt = min(end - base, 64);
        int c = N_NODES;
        if (lane < cnt) c = col[base + lane];
        sc[w][lane] = c;
        int nb = (cnt + 7) >> 3;
        for (int j8 = 0; j8 < nb; ++j8) {
            int j = j8 << 3;
            int r0 = sc[w][j + h];
            int r1 = sc[w][j + 4 + h];
            uint2 v0 = ((const uint2*)(t + (size_t)r0 * 64))[k];
            uint2 v1 = ((const uint2*)(t + (size_t)r1 * 64))[k];
            a0 += bf_lo(v0.x) + bf_lo(v1.x);
            a1 += bf_hi(v0.x) + bf_hi(v1.x);
            a2 += bf_lo(v0.y) + bf_lo(v1.y);
            a3 += bf_hi(v0.y) + bf_hi(v1.y);
        }
    }
    a0 += __shfl_xor(a0, 16); a0 += __shfl_xor(a0, 32);
    a1 += __shfl_xor(a1, 16); a1 += __shfl_xor(a1, 32);
    a2 += __shfl_xor(a2, 16); a2 += __shfl_xor(a2, 32);
    a3 += __shfl_xor(a3, 16); a3 += __shfl_xor(a3, 32);
    if (h == 0) {
        float di = dinv[wid];
        float4 bb = ((const float4*)b)[k];
        float o0 = fmaf(di, a0, bb.x);
        float o1 = fmaf(di, a1, bb.y);
        float o2 = fmaf(di, a2, bb.z);
        float o3 = fmaf(di, a3, bb.w);
        unsigned long long pv = (unsigned long long)pack2(o0, o1)
                              | ((unsigned long long)pack2(o2, o3) << 32);
        __builtin_nontemporal_store(pv,
            (unsigned long long*)(outbuf + (size_t)wid * 32) + k);
    }
}

// ---------------- decode: z is bf16 [N x 64] ----------------
__global__ void k_decode(const int* __restrict__ eli, const ushort16* __restrict__ z,
                         float* __restrict__ out) {
    int e = blockIdx.x * blockDim.x + threadIdx.x;
    if (e >= N_EL) return;
    int a = eli[e];
    int b = eli[N_EL + e];
    const uint4* za = (const uint4*)(z + (size_t)a * 64);
    const uint4* zb = (const uint4*)(z + (size_t)b * 64);
    float acc = 0.0f;
#pragma unroll
    for (int i = 0; i < 8; ++i) {
        uint4 va = za[i], vb = zb[i];
        acc += bf_lo(va.x) * bf_lo(vb.x) + bf_hi(va.x) * bf_hi(vb.x);
        acc += bf_lo(va.y) * bf_lo(vb.y) + bf_hi(va.y) * bf_hi(vb.y);
        acc += bf_lo(va.z) * bf_lo(vb.z) + bf_hi(va.z) * bf_hi(vb.z);
        acc += bf_lo(va.w) * bf_lo(vb.w) + bf_hi(va.w) * bf_hi(vb.w);
    }
    out[e] = acc;
}

extern "C" void kernel_launch(void* const* d_in, const int* in_sizes, int n_in,
                              void* d_out, int out_size, void* d_ws, size_t ws_size,
                              hipStream_t stream) {
    const float* x   = (const float*)d_in[0];
    const int*   ei  = (const int*)d_in[1];
    const int*   eli = (const int*)d_in[2];
    const float* W1  = (const float*)d_in[3];
    const float* b1  = (const float*)d_in[4];
    const float* W2  = (const float*)d_in[5];
    const float* b2  = (const float*)d_in[6];
    const float* W3  = (const float*)d_in[7];
    const float* b3  = (const float*)d_in[8];
    float* out = (float*)d_out;

    const int* srcA = ei;
    const int* dstA = ei + N_EDGES;

    // workspace layout (bytes):
    //   dinv [0, 400K)       rowptr [1M, +400K+4)
    //   TT [1.5M, +3128)  BB [1.6M, +3132)  cnt [1.75M, +4)
    //   col [2M, +6.4M)
    //   H  [9M, +2.45M)   CO [12M, +2.45M)
    //   ed [16M, +12.8M)
    //   t  [32M, +25.6M+256)   (bf16 N x 128 + zero pad row)
    //   aggb [60M, +25.6M)     (bf16 N x 128 layers; N x 64 final z)
    char* ws = (char*)d_ws;
    float*      dinv   = (float*)    (ws + 0);
    int*        rowptr = (int*)      (ws + (1024u << 10));
    int*        TT     = (int*)      (ws + (1536u << 10));
    int*        BB     = (int*)      (ws + (1638u << 10));
    int*        cnt    = (int*)      (ws + (1792u << 10));
    int*        col    = (int*)      (ws + (2048u << 10));
    int*        H      = (int*)      (ws + (9u << 20));
    int*        CO     = (int*)      (ws + (12u << 20));
    long long*  ed     = (long long*)(ws + (16u << 20));
    ushort16*   t      = (ushort16*) (ws + (32u << 20));
    ushort16*   aggb   = (ushort16*) (ws + (60u << 20));

    const int B = 256;
    const int gG  = (N_NODES * 64 + B - 1) / B;
    const int gEL = (N_EL + B - 1) / B;

    hipMemsetAsync(cnt, 0, 4, stream);
    hipMemsetAsync((char*)t + (size_t)N_NODES * 256, 0, 256, stream);  // pad row

    // ---- GEMM1 + chunk histograms (interleaved), then atomic-free CSR ----
    k_fat1<<<GRID_FAT, B, 0, stream>>>(x, W1, t, dstA, H);
    k_scanB<<<NBKT, B, 0, stream>>>(H, CO, TT, BB, cnt);
    k_csrC<<<NCHK, B, 0, stream>>>(srcA, dstA, CO, BB, ed);
    k_csrD<<<NBKT, B, 0, stream>>>(ed, BB, rowptr, dinv, col, (uint32*)t);

    // ---- layer 1 aggregation (t prescaled by csrD) ----
    k_gather128<true><<<gG, B, 0, stream>>>(rowptr, col, dinv, (const uint32*)t,
                                            b1, (uint32*)aggb);
    // ---- layer 2 (epilogue prescales by dinv) ----
    k_gemm_mfma<128, ushort16, true, 128><<<GT_GEMM, B, 0, stream>>>(aggb, W2, dinv, t);
    k_gather128<true><<<gG, B, 0, stream>>>(rowptr, col, dinv, (const uint32*)t,
                                            b2, (uint32*)aggb);
    // ---- layer 3 (OS=128 so pad row is shared) ----
    k_gemm_mfma<64, ushort16, true, 128><<<GT_GEMM, B, 0, stream>>>(aggb, W3, dinv, t);
    k_gather64<<<gG, B, 0, stream>>>(rowptr, col, dinv, (const uint32*)t, b3,
                                     (uint32*)aggb);

    // ---- decode ----
    k_decode<<<gEL, B, 0, stream>>>(eli, aggb, out);
}